// Round 16
// baseline (815.310 us; speedup 1.0000x reference)
//
#include <hip/hip_runtime.h>
#include <stdint.h>

#define D_MODEL 1024
#define HID     4096
#define NE      8
#define NTOK    8192
#define NSLOT   (NTOK*2)
#define TM      128
#define MAX_RB  136            // padded regions fit in 136 row-blocks of 128
#define MPAD    (MAX_RB*TM)
#define HHALF   2048           // hidden split in 2 passes (L3-hot h-half schedule)
#define GATE_BLOCKS 256        // 32 tokens/block, 8 lanes/token

typedef unsigned short u16;
typedef __attribute__((ext_vector_type(8))) __bf16 bf16x8;
typedef __attribute__((ext_vector_type(4))) float  f32x4;

__device__ __forceinline__ u16 f2bu(float f){
  uint32_t u = __builtin_bit_cast(uint32_t, f);
  uint32_t r = (u + 0x7FFFu + ((u >> 16) & 1u)) >> 16;   // RNE
  return (u16)r;
}
__device__ __forceinline__ float b2f(u16 v){
  uint32_t u = ((uint32_t)v) << 16;
  return __builtin_bit_cast(float, u);
}

// async global -> LDS, 16 B per lane; lds base must be wave-uniform
__device__ __forceinline__ void gload16(const u16* src, u16* lds){
  __builtin_amdgcn_global_load_lds((const __attribute__((address_space(1))) void*)src,
                                   (__attribute__((address_space(3))) void*)lds, 16, 0, 0);
}

// bijective chunked XCD swizzle (nwg % 8 == 0)
__device__ __forceinline__ int xcd_swz(int w, int nwg){
  int q = nwg >> 3;
  return (w & 7) * q + (w >> 3);
}

// counted waits + raw barriers (T4): loads stay in flight across barriers
#define WAITV(n) do{ asm volatile("s_waitcnt vmcnt(" #n ")" ::: "memory"); \
                     __builtin_amdgcn_sched_barrier(0); }while(0)
#define BARX()   do{ __builtin_amdgcn_sched_barrier(0); \
                     __builtin_amdgcn_s_barrier(); \
                     __builtin_amdgcn_sched_barrier(0); }while(0)

// ---- prep: W1/W2 transpose+cvt AND gate, one fused launch ----
// grid: [0,16384) W1 tiles, [16384,32768) W2 tiles, [32768,33024) gate blocks.
__global__ __launch_bounds__(256) void prep_kernel(
    const float* __restrict__ x, const float* __restrict__ Wg, const float* __restrict__ bg,
    const float* __restrict__ W1, const float* __restrict__ W2,
    u16* __restrict__ w1t, u16* __restrict__ w2t,
    int* __restrict__ topk, float* __restrict__ gates, u16* __restrict__ x16,
    float* __restrict__ part_probs, float* __restrict__ part_assign, int* __restrict__ part_cnt)
{
  int id = blockIdx.x;
  int t = threadIdx.x;
  if (id < 32768){
    // ---- transpose+cvt region: in[e][R][C] -> out[e][C][R], 64x32 tiles ----
    __shared__ float tile[64][33];
    const float* in; u16* out; int R, C, r0, c0, e;
    if (id < 16384){
      int bx = id & 127, by = (id >> 7) & 15; e = id >> 11;
      R = D_MODEL; C = HID; r0 = by*64; c0 = bx*32;
      in = W1; out = w1t;
    } else {
      int j = id - 16384;
      int bx = j & 31, by = (j >> 5) & 63; e = j >> 11;
      R = HID; C = D_MODEL; r0 = by*64; c0 = bx*32;
      in = W2; out = w2t;
    }
    const float* src = in + (size_t)e * R * C;
    u16* dst = out + (size_t)e * R * C;
    int rr = t >> 3;            // 0..31
    int tc4 = (t & 7) * 4;      // 0..28
#pragma unroll
    for (int p = 0; p < 2; p++){
      int r = rr + p*32;
      float4 v = *(const float4*)(src + (size_t)(r0 + r) * C + c0 + tc4);
      tile[r][tc4+0] = v.x; tile[r][tc4+1] = v.y;
      tile[r][tc4+2] = v.z; tile[r][tc4+3] = v.w;
    }
    __syncthreads();
    int c = t >> 3;             // output row (a column of the input tile)
    int seg = (t & 7) * 8;
    u16 o[8];
#pragma unroll
    for (int j = 0; j < 8; j++) o[j] = f2bu(tile[seg + j][c]);
    *(int4*)(dst + (size_t)(c0 + c) * R + r0 + seg) = *(int4*)o;
    return;
  }
  // ---- gate region: 8 lanes/token, shfl butterfly; x->bf16 fused ----
  int gb = id - 32768;
  __shared__ float sp[32][8];
  __shared__ float sa[32][8];
  __shared__ int   sc[32][8];
  int tb = t >> 3;                  // token within block (0..31)
  int g  = t & 7;                   // lane within token group
  int n  = gb * 32 + tb;
  const float* xr = x + (size_t)n * D_MODEL;
  u16* xo = x16 + (size_t)n * D_MODEL;
  float lg[8];
#pragma unroll
  for (int e = 0; e < 8; e++) lg[e] = 0.f;
  for (int k = 0; k < 32; k++){
    int off = k*32 + g*4;           // lanes of a group cover one 128B segment
    float4 v = *(const float4*)(xr + off);
    const float* wr = Wg + (size_t)off * 8;
#pragma unroll
    for (int e = 0; e < 8; e++)
      lg[e] += v.x*wr[e] + v.y*wr[8+e] + v.z*wr[16+e] + v.w*wr[24+e];
    u16 o[4] = {f2bu(v.x), f2bu(v.y), f2bu(v.z), f2bu(v.w)};
    *(uint2*)(xo + off) = *(const uint2*)o;
  }
#pragma unroll
  for (int m = 1; m < 8; m <<= 1)
#pragma unroll
    for (int e = 0; e < 8; e++) lg[e] += __shfl_xor(lg[e], m);
#pragma unroll
  for (int e = 0; e < 8; e++) lg[e] += bg[e];

  float mx = lg[0];
#pragma unroll
  for (int e = 1; e < 8; e++) mx = fmaxf(mx, lg[e]);
  float p[8]; float s = 0.f;
#pragma unroll
  for (int e = 0; e < 8; e++){ p[e] = expf(lg[e]-mx); s += p[e]; }
  float inv = 1.f / s;
  int bi = 0; float best = lg[0];
#pragma unroll
  for (int e = 1; e < 8; e++) if (lg[e] > best){ best = lg[e]; bi = e; }
  int bi2 = 0; float best2 = -3.0e38f;
#pragma unroll
  for (int e = 0; e < 8; e++) if (e != bi && lg[e] > best2){ best2 = lg[e]; bi2 = e; }
  float t1 = expf(best2 - best);
  float g0 = 1.f / (1.f + t1);
  float g1 = t1 / (1.f + t1);
  if (g == 0){
    topk[2*n] = bi;  topk[2*n+1] = bi2;
    gates[2*n] = g0; gates[2*n+1] = g1;
#pragma unroll
    for (int e = 0; e < 8; e++){
      sp[tb][e] = p[e] * inv;
      sa[tb][e] = (e == bi) ? g0 : ((e == bi2) ? g1 : 0.f);
      sc[tb][e] = (e == bi || e == bi2) ? 1 : 0;
    }
  }
  __syncthreads();
  if (t < 8){
    float s2 = 0.f; for (int i = 0; i < 32; i++) s2 += sp[i][t];
    part_probs[gb*8 + t] = s2;
  } else if (t < 16){
    int e = t - 8; float s2 = 0.f; for (int i = 0; i < 32; i++) s2 += sa[i][e];
    part_assign[gb*8 + e] = s2;
  } else if (t < 24){
    int e = t - 16; int c = 0; for (int i = 0; i < 32; i++) c += sc[i][e];
    part_cnt[gb*8 + e] = c;
  }
}

// ---- scan: counts, padded offsets, block->expert table, routed init ----
__global__ __launch_bounds__(256) void scan_kernel(const int* __restrict__ part_cnt,
                                                   int* __restrict__ counts,
                                                   int* __restrict__ padded_off,
                                                   int* __restrict__ cursor,
                                                   int* __restrict__ block_expert,
                                                   int* __restrict__ routed)
{
  __shared__ int off[NE+1];
  int t = threadIdx.x;
  if (t == 0){
    int o = 0; off[0] = 0;
    for (int e = 0; e < NE; e++){
      int c = 0;
      for (int b = 0; b < GATE_BLOCKS; b++) c += part_cnt[b*8 + e];
      counts[e] = c;
      o += ((c + TM - 1) / TM) * TM;
      off[e+1] = o;
    }
    for (int e = 0; e <= NE; e++) padded_off[e] = off[e];
  }
  __syncthreads();
  if (t < NE) cursor[t] = 0;
  for (int rb = t; rb < MAX_RB; rb += 256){
    int e = -1;
    int r = rb * TM;
    for (int j = 0; j < NE; j++)
      if (r >= off[j] && r < off[j+1]) e = j;
    block_expert[rb] = e;
  }
  for (int i = t; i < MPAD; i += 256) routed[i] = -1;
}

__global__ __launch_bounds__(256) void place_kernel(const int* __restrict__ topk,
                                                    const int* __restrict__ padded_off,
                                                    int* __restrict__ cursor,
                                                    int* __restrict__ routed)
{
  int s = blockIdx.x * 256 + threadIdx.x;   // slot id = n*2 + k
  int e = topk[s];
  int pos = padded_off[e] + atomicAdd(&cursor[e], 1);
  routed[pos] = s;
}

// ===== GEMMs: 128x128 tile, 4 waves, depth-2 counted-vmcnt (2 bufs, 32KB LDS
// -> 4-5 blocks/CU), chunk-XOR swizzle. R7 half-split schedule (h L3-hot). =====

// ---- GEMM1: h = relu(Xg @ W1[e] + b1[e]) for one hidden half ----
__global__ __launch_bounds__(256, 5) void gemm1_kernel(
    const u16* __restrict__ x16, const u16* __restrict__ w1t, const float* __restrict__ b1,
    const int* __restrict__ routed, const int* __restrict__ block_expert,
    u16* __restrict__ h, int half)
{
  int l = xcd_swz(blockIdx.x, gridDim.x);
  int rb = l >> 4, cb = l & 15;            // NCB = 16
  int e = block_expert[rb];
  if (e < 0) return;
  __shared__ __align__(16) u16 Al[2][128][32];
  __shared__ __align__(16) u16 Bl[2][128][32];
  u16* AF = &Al[0][0][0];
  u16* BF = &Bl[0][0][0];
  int t = threadIdx.x;
  int lane = t & 63, wid = t >> 6;

  int srow0 = wid*32 + (lane >> 2);
  // write-side swizzle: pre-swizzled global source column chunk (LDS dest linear)
  int sch = ((lane & 3) ^ ((lane >> 3) & 3)) * 8;

  int slot0 = routed[rb*TM + srow0];
  int slot1 = routed[rb*TM + srow0 + 16];
  int tok0 = slot0 >= 0 ? (slot0 >> 1) : 0;
  int tok1 = slot1 >= 0 ? (slot1 >> 1) : 0;
  const u16* srcA0 = x16 + (size_t)tok0 * D_MODEL + sch;
  const u16* srcA1 = x16 + (size_t)tok1 * D_MODEL + sch;
  const u16* wb = w1t + ((size_t)e*HID + (size_t)half*HHALF + (size_t)cb*128) * D_MODEL + sch;
  const u16* srcB0 = wb + (size_t)srow0 * D_MODEL;
  const u16* srcB1 = wb + (size_t)(srow0 + 16) * D_MODEL;

  int wr = wid >> 1, wc = wid & 1;
  int fr = lane & 15, fk = lane >> 4;
  int fkx8 = (fk ^ ((fr >> 1) & 3)) * 8;   // read-side swizzle (uniform per lane)
  f32x4 acc[4][4];
#pragma unroll
  for (int i = 0; i < 4; i++)
#pragma unroll
    for (int j = 0; j < 4; j++) acc[i][j] = (f32x4){0.f,0.f,0.f,0.f};

#define STG1(bo, kk) do{ \
    gload16(srcA0 + (kk), AF + (bo) + wid*1024); \
    gload16(srcA1 + (kk), AF + (bo) + wid*1024 + 512); \
    gload16(srcB0 + (kk), BF + (bo) + wid*1024); \
    gload16(srcB1 + (kk), BF + (bo) + wid*1024 + 512); } while(0)

#define CMP1(bo) do{ \
    bf16x8 af[4], bf[4]; \
    _Pragma("unroll") \
    for (int mm = 0; mm < 4; mm++) af[mm] = *(const bf16x8*)(AF + (bo) + (wr*64 + mm*16 + fr)*32 + fkx8); \
    _Pragma("unroll") \
    for (int nn = 0; nn < 4; nn++) bf[nn] = *(const bf16x8*)(BF + (bo) + (wc*64 + nn*16 + fr)*32 + fkx8); \
    _Pragma("unroll") \
    for (int mm = 0; mm < 4; mm++) \
      _Pragma("unroll") \
      for (int nn = 0; nn < 4; nn++) \
        acc[mm][nn] = __builtin_amdgcn_mfma_f32_16x16x32_bf16(af[mm], bf[nn], acc[mm][nn], 0, 0, 0); } while(0)

  const int nk = D_MODEL/32;               // 32 K-steps
  STG1(0, 0); STG1(4096, 32);
  int bo = 0;
  for (int i = 0; i < nk - 1; i++){
    WAITV(4);                              // stage i landed; i+1 in flight
    BARX();
    CMP1(bo);
    BARX();                                // all waves done reading buf bo
    if (i + 2 < nk) STG1(bo, (i+2)*32);
    bo ^= 4096;
  }
  WAITV(0); BARX(); CMP1(bo);

  int r4 = fk * 4;
#pragma unroll
  for (int nn = 0; nn < 4; nn++){
    int ct = wc*64 + nn*16 + fr;
    float bias = b1[(size_t)e*HID + (size_t)half*HHALF + cb*128 + ct];
#pragma unroll
    for (int mm = 0; mm < 4; mm++){
#pragma unroll
      for (int r = 0; r < 4; r++){
        int rt = wr*64 + mm*16 + r4 + r;
        float v = acc[mm][nn][r] + bias;
        v = v > 0.f ? v : 0.f;
        h[(size_t)(rb*TM + rt) * HHALF + cb*128 + ct] = f2bu(v);
      }
    }
  }
#undef STG1
#undef CMP1
}

// ---- GEMM2: y[slot] (+)= gate * (h @ W2[e]) for one hidden half; y is bf16 ----
__global__ __launch_bounds__(256, 5) void gemm2_kernel(
    const u16* __restrict__ h, const u16* __restrict__ w2t,
    const int* __restrict__ routed, const int* __restrict__ block_expert,
    const float* __restrict__ gates, u16* __restrict__ y, int half)
{
  int l = xcd_swz(blockIdx.x, gridDim.x);
  int rb = l >> 3, cb = l & 7;             // NCB = 8
  int e = block_expert[rb];
  if (e < 0) return;
  __shared__ __align__(16) u16 Al[2][128][32];
  __shared__ __align__(16) u16 Bl[2][128][32];
  __shared__ int   rslot[128];
  __shared__ float rgate[128];
  u16* AF = &Al[0][0][0];
  u16* BF = &Bl[0][0][0];
  int t = threadIdx.x;
  int lane = t & 63, wid = t >> 6;
  if (t < 128){
    int s = routed[rb*TM + t];
    rslot[t] = s;
    rgate[t] = (s >= 0) ? gates[s] : 0.f;
  }

  int srow0 = wid*32 + (lane >> 2);
  int sch = ((lane & 3) ^ ((lane >> 3) & 3)) * 8;
  const u16* srcA0 = h + (size_t)(rb*TM + srow0) * HHALF + sch;
  const u16* srcA1 = h + (size_t)(rb*TM + srow0 + 16) * HHALF + sch;
  const u16* wb = w2t + ((size_t)e*D_MODEL + (size_t)cb*128) * HID + (size_t)half*HHALF + sch;
  const u16* srcB0 = wb + (size_t)srow0 * HID;
  const u16* srcB1 = wb + (size_t)(srow0 + 16) * HID;

  int wr = wid >> 1, wc = wid & 1;
  int fr = lane & 15, fk = lane >> 4;
  int fkx8 = (fk ^ ((fr >> 1) & 3)) * 8;
  f32x4 acc[4][4];
#pragma unroll
  for (int i = 0; i < 4; i++)
#pragma unroll
    for (int j = 0; j < 4; j++) acc[i][j] = (f32x4){0.f,0.f,0.f,0.f};

#define STG2(bo, kk) do{ \
    gload16(srcA0 + (kk), AF + (bo) + wid*1024); \
    gload16(srcA1 + (kk), AF + (bo) + wid*1024 + 512); \
    gload16(srcB0 + (kk), BF + (bo) + wid*1024); \
    gload16(srcB1 + (kk), BF + (bo) + wid*1024 + 512); } while(0)

#define CMP2(bo) do{ \
    bf16x8 af[4], bf[4]; \
    _Pragma("unroll") \
    for (int mm = 0; mm < 4; mm++) af[mm] = *(const bf16x8*)(AF + (bo) + (wr*64 + mm*16 + fr)*32 + fkx8); \
    _Pragma("unroll") \
    for (int nn = 0; nn < 4; nn++) bf[nn] = *(const bf16x8*)(BF + (bo) + (wc*64 + nn*16 + fr)*32 + fkx8); \
    _Pragma("unroll") \
    for (int mm = 0; mm < 4; mm++) \
      _Pragma("unroll") \
      for (int nn = 0; nn < 4; nn++) \
        acc[mm][nn] = __builtin_amdgcn_mfma_f32_16x16x32_bf16(af[mm], bf[nn], acc[mm][nn], 0, 0, 0); } while(0)

  const int nk = HHALF/32;                 // 64 K-steps
  STG2(0, 0); STG2(4096, 32);
  int bo = 0;
  for (int i = 0; i < nk - 1; i++){
    WAITV(4);
    BARX();
    CMP2(bo);
    BARX();
    if (i + 2 < nk) STG2(bo, (i+2)*32);
    bo ^= 4096;
  }
  WAITV(0); BARX(); CMP2(bo);

  int r4 = fk * 4;
#pragma unroll
  for (int mm = 0; mm < 4; mm++){
#pragma unroll
    for (int r = 0; r < 4; r++){
      int rt = wr*64 + mm*16 + r4 + r;
      int slot = rslot[rt];
      if (slot < 0) continue;
      float g = rgate[rt];
#pragma unroll
      for (int nn = 0; nn < 4; nn++){
        int ct = wc*64 + nn*16 + fr;
        size_t idx = (size_t)slot * D_MODEL + cb*128 + ct;
        float val = g * acc[mm][nn][r];
        if (half == 0) y[idx] = f2bu(val);
        else           y[idx] = f2bu(b2f(y[idx]) + val);
      }
    }
  }
#undef STG2
#undef CMP2
}

// ---- combine: out[n] = y[slot0] + y[slot1] + g0*b2[e0] + g1*b2[e1] (y bf16) ----
__global__ __launch_bounds__(256) void combine_kernel(
    const u16* __restrict__ y, const int* __restrict__ topk, const float* __restrict__ gates,
    const float* __restrict__ b2, float* __restrict__ out)
{
  int i = blockIdx.x * 256 + threadIdx.x;
  int n = i >> 8;
  int d = (i & 255) * 4;
  ushort4 a4 = *(const ushort4*)(y + (size_t)(2*n)   * D_MODEL + d);
  ushort4 b4 = *(const ushort4*)(y + (size_t)(2*n+1) * D_MODEL + d);
  int e0 = topk[2*n], e1 = topk[2*n+1];
  float g0 = gates[2*n], g1 = gates[2*n+1];
  float4 c0 = *(const float4*)(b2 + (size_t)e0 * D_MODEL + d);
  float4 c1 = *(const float4*)(b2 + (size_t)e1 * D_MODEL + d);
  float4 o;
  o.x = b2f(a4.x) + b2f(b4.x) + g0*c0.x + g1*c1.x;
  o.y = b2f(a4.y) + b2f(b4.y) + g0*c0.y + g1*c1.y;
  o.z = b2f(a4.z) + b2f(b4.z) + g0*c0.z + g1*c1.z;
  o.w = b2f(a4.w) + b2f(b4.w) + g0*c0.w + g1*c1.w;
  *(float4*)(out + (size_t)n * D_MODEL + d) = o;
}

__global__ void finalize_kernel(const float* __restrict__ part_probs,
                                const float* __restrict__ part_assign,
                                const int* __restrict__ counts,
                                float* __restrict__ out_tail)
{
  __shared__ float ep[8], af[8];
  int t = threadIdx.x;
  if (t < 8){
    float s = 0.f;
    for (int b = 0; b < GATE_BLOCKS; b++) s += part_probs[b*8 + t];
    ep[t] = s / (float)NTOK;
  } else if (t < 16){
    int e = t - 8; float s = 0.f;
    for (int b = 0; b < GATE_BLOCKS; b++) s += part_assign[b*8 + e];
    af[e] = s / (float)NTOK;
  }
  __syncthreads();
  if (t == 0){
    float loss = 0.f;
    for (int e = 0; e < 8; e++) loss += ep[e] * af[e];
    out_tail[0] = loss * (float)NE;
  }
  if (t < 8){
    out_tail[1 + t]  = (float)counts[t];
    out_tail[9 + t]  = ep[t];
    out_tail[17 + t] = af[t];
  }
}

extern "C" void kernel_launch(void* const* d_in, const int* in_sizes, int n_in,
                              void* d_out, int out_size, void* d_ws, size_t ws_size,
                              hipStream_t stream)
{
  const float* x  = (const float*)d_in[0];
  const float* Wg = (const float*)d_in[1];
  const float* bg = (const float*)d_in[2];
  const float* W1 = (const float*)d_in[3];
  const float* b1 = (const float*)d_in[4];
  const float* W2 = (const float*)d_in[5];
  const float* b2 = (const float*)d_in[6];
  float* out = (float*)d_out;

  char* ws = (char*)d_ws;
  size_t o = 0;
  auto alloc = [&](size_t bytes) -> char* {
    char* p = ws + o; o = (o + bytes + 255) & ~(size_t)255; return p;
  };
  int*   topk        = (int*)   alloc((size_t)NSLOT*4);
  float* gates       = (float*) alloc((size_t)NSLOT*4);
  int*   counts      = (int*)   alloc(NE*4);
  int*   padded_off  = (int*)   alloc((NE+1)*4);
  int*   cursor      = (int*)   alloc(NE*4);
  int*   block_exp   = (int*)   alloc(MAX_RB*4);
  int*   routed      = (int*)   alloc((size_t)MPAD*4);
  float* part_probs  = (float*) alloc(GATE_BLOCKS*8*4);
  float* part_assign = (float*) alloc(GATE_BLOCKS*8*4);
  int*   part_cnt    = (int*)   alloc(GATE_BLOCKS*8*4);
  u16*   x16         = (u16*)   alloc((size_t)NTOK*D_MODEL*2);
  u16*   w1t         = (u16*)   alloc((size_t)NE*HID*D_MODEL*2);
  u16*   w2t         = (u16*)   alloc((size_t)NE*HID*D_MODEL*2);
  u16*   hbuf        = (u16*)   alloc((size_t)MPAD*HHALF*2);
  u16*   ybuf        = (u16*)   alloc((size_t)NSLOT*D_MODEL*2);
  (void)ws_size; (void)in_sizes; (void)n_in; (void)out_size;

  prep_kernel<<<33024, 256, 0, stream>>>(x, Wg, bg, W1, W2, w1t, w2t,
                                         topk, gates, x16, part_probs, part_assign, part_cnt);
  scan_kernel<<<1, 256, 0, stream>>>(part_cnt, counts, padded_off, cursor, block_exp, routed);
  place_kernel<<<NSLOT/256, 256, 0, stream>>>(topk, padded_off, cursor, routed);
  for (int half = 0; half < 2; half++){
    gemm1_kernel<<<16*MAX_RB, 256, 0, stream>>>(x16, w1t, b1, routed, block_exp, hbuf, half);
    gemm2_kernel<<<8*MAX_RB, 256, 0, stream>>>(hbuf, w2t, routed, block_exp, gates, ybuf, half);
  }
  combine_kernel<<<NTOK, 256, 0, stream>>>(ybuf, topk, gates, b2, out);
  finalize_kernel<<<1, 64, 0, stream>>>(part_probs, part_assign, counts, out + (size_t)NTOK*D_MODEL);
}

// Round 17
// 731.005 us; speedup vs baseline: 1.1153x; 1.1153x over previous
//
#include <hip/hip_runtime.h>
#include <stdint.h>

#define D_MODEL 1024
#define HID     4096
#define NE      8
#define NTOK    8192
#define NSLOT   (NTOK*2)
#define TM      128
#define MAX_RB  136            // padded regions fit in 136 row-blocks of 128
#define MPAD    (MAX_RB*TM)
#define HHALF   2048           // hidden split in 2 passes (L3-hot h-half schedule)
#define GATE_BLOCKS 256        // 32 tokens/block, 8 lanes/token

typedef unsigned short u16;
typedef __attribute__((ext_vector_type(8))) __bf16 bf16x8;
typedef __attribute__((ext_vector_type(4))) float  f32x4;

__device__ __forceinline__ u16 f2bu(float f){
  uint32_t u = __builtin_bit_cast(uint32_t, f);
  uint32_t r = (u + 0x7FFFu + ((u >> 16) & 1u)) >> 16;   // RNE
  return (u16)r;
}
__device__ __forceinline__ float b2f(u16 v){
  uint32_t u = ((uint32_t)v) << 16;
  return __builtin_bit_cast(float, u);
}

// async global -> LDS, 16 B per lane; lds base must be wave-uniform
__device__ __forceinline__ void gload16(const u16* src, u16* lds){
  __builtin_amdgcn_global_load_lds((const __attribute__((address_space(1))) void*)src,
                                   (__attribute__((address_space(3))) void*)lds, 16, 0, 0);
}

// bijective chunked XCD swizzle (nwg % 8 == 0)
__device__ __forceinline__ int xcd_swz(int w, int nwg){
  int q = nwg >> 3;
  return (w & 7) * q + (w >> 3);
}

// counted waits + raw barriers (T4): loads stay in flight across barriers
#define WAITV(n) do{ asm volatile("s_waitcnt vmcnt(" #n ")" ::: "memory"); \
                     __builtin_amdgcn_sched_barrier(0); }while(0)
#define BARX()   do{ __builtin_amdgcn_sched_barrier(0); \
                     __builtin_amdgcn_s_barrier(); \
                     __builtin_amdgcn_sched_barrier(0); }while(0)

// ---- transpose + fp32->bf16 cast: in[e][R][C] -> out[e][C][R] ----
__global__ __launch_bounds__(256) void transpose_cvt(const float* __restrict__ in,
                                                     u16* __restrict__ out, int R, int C)
{
  __shared__ float tile[64][33];
  int e = blockIdx.z;
  int r0 = blockIdx.y * 64, c0 = blockIdx.x * 32;
  const float* src = in + (size_t)e * R * C;
  u16* dst = out + (size_t)e * R * C;
  int t = threadIdx.x;
  int rr = t >> 3;            // 0..31
  int tc4 = (t & 7) * 4;      // 0..28
#pragma unroll
  for (int p = 0; p < 2; p++){
    int r = rr + p*32;
    float4 v = *(const float4*)(src + (size_t)(r0 + r) * C + c0 + tc4);
    tile[r][tc4+0] = v.x; tile[r][tc4+1] = v.y;
    tile[r][tc4+2] = v.z; tile[r][tc4+3] = v.w;
  }
  __syncthreads();
  int c = t >> 3;             // 0..31 output row (a column of the input tile)
  int seg = (t & 7) * 8;      // r-segment start
  u16 o[8];
#pragma unroll
  for (int j = 0; j < 8; j++) o[j] = f2bu(tile[seg + j][c]);
  *(int4*)(dst + (size_t)(c0 + c) * R + r0 + seg) = *(int4*)o;
}

// ---- gate: 8 lanes/token; logits via shfl butterfly; x->bf16 fused ----
__global__ __launch_bounds__(256) void gate_kernel(
    const float* __restrict__ x, const float* __restrict__ Wg, const float* __restrict__ bg,
    int* __restrict__ topk, float* __restrict__ gates, u16* __restrict__ x16,
    float* __restrict__ part_probs, float* __restrict__ part_assign, int* __restrict__ part_cnt)
{
  __shared__ float sp[32][8];
  __shared__ float sa[32][8];
  __shared__ int   sc[32][8];
  int t = threadIdx.x;
  int tb = t >> 3;                  // token within block (0..31)
  int g  = t & 7;                   // lane within token group
  int n  = blockIdx.x * 32 + tb;
  const float* xr = x + (size_t)n * D_MODEL;
  u16* xo = x16 + (size_t)n * D_MODEL;
  float lg[8];
#pragma unroll
  for (int e = 0; e < 8; e++) lg[e] = 0.f;
  for (int k = 0; k < 32; k++){
    int off = k*32 + g*4;           // lanes of a group cover one 128B segment
    float4 v = *(const float4*)(xr + off);
    const float* wr = Wg + (size_t)off * 8;
#pragma unroll
    for (int e = 0; e < 8; e++)
      lg[e] += v.x*wr[e] + v.y*wr[8+e] + v.z*wr[16+e] + v.w*wr[24+e];
    u16 o[4] = {f2bu(v.x), f2bu(v.y), f2bu(v.z), f2bu(v.w)};
    *(uint2*)(xo + off) = *(const uint2*)o;
  }
  // butterfly reduce across the 8-lane group (masks 1,2,4 stay in-group)
#pragma unroll
  for (int m = 1; m < 8; m <<= 1)
#pragma unroll
    for (int e = 0; e < 8; e++) lg[e] += __shfl_xor(lg[e], m);
#pragma unroll
  for (int e = 0; e < 8; e++) lg[e] += bg[e];

  float mx = lg[0];
#pragma unroll
  for (int e = 1; e < 8; e++) mx = fmaxf(mx, lg[e]);
  float p[8]; float s = 0.f;
#pragma unroll
  for (int e = 0; e < 8; e++){ p[e] = expf(lg[e]-mx); s += p[e]; }
  float inv = 1.f / s;
  int bi = 0; float best = lg[0];
#pragma unroll
  for (int e = 1; e < 8; e++) if (lg[e] > best){ best = lg[e]; bi = e; }
  int bi2 = 0; float best2 = -3.0e38f;
#pragma unroll
  for (int e = 0; e < 8; e++) if (e != bi && lg[e] > best2){ best2 = lg[e]; bi2 = e; }
  float t1 = expf(best2 - best);
  float g0 = 1.f / (1.f + t1);
  float g1 = t1 / (1.f + t1);
  if (g == 0){
    topk[2*n] = bi;  topk[2*n+1] = bi2;
    gates[2*n] = g0; gates[2*n+1] = g1;
#pragma unroll
    for (int e = 0; e < 8; e++){
      sp[tb][e] = p[e] * inv;
      sa[tb][e] = (e == bi) ? g0 : ((e == bi2) ? g1 : 0.f);
      sc[tb][e] = (e == bi || e == bi2) ? 1 : 0;
    }
  }
  __syncthreads();
  if (t < 8){
    float s2 = 0.f; for (int i = 0; i < 32; i++) s2 += sp[i][t];
    part_probs[blockIdx.x*8 + t] = s2;
  } else if (t < 16){
    int e = t - 8; float s2 = 0.f; for (int i = 0; i < 32; i++) s2 += sa[i][e];
    part_assign[blockIdx.x*8 + e] = s2;
  } else if (t < 24){
    int e = t - 16; int c = 0; for (int i = 0; i < 32; i++) c += sc[i][e];
    part_cnt[blockIdx.x*8 + e] = c;
  }
}

// ---- scan: counts, padded offsets, block->expert table, routed init ----
__global__ __launch_bounds__(256) void scan_kernel(const int* __restrict__ part_cnt,
                                                   int* __restrict__ counts,
                                                   int* __restrict__ padded_off,
                                                   int* __restrict__ cursor,
                                                   int* __restrict__ block_expert,
                                                   int* __restrict__ routed)
{
  __shared__ int off[NE+1];
  int t = threadIdx.x;
  if (t == 0){
    int o = 0; off[0] = 0;
    for (int e = 0; e < NE; e++){
      int c = 0;
      for (int b = 0; b < GATE_BLOCKS; b++) c += part_cnt[b*8 + e];
      counts[e] = c;
      o += ((c + TM - 1) / TM) * TM;
      off[e+1] = o;
    }
    for (int e = 0; e <= NE; e++) padded_off[e] = off[e];
  }
  __syncthreads();
  if (t < NE) cursor[t] = 0;
  for (int rb = t; rb < MAX_RB; rb += 256){
    int e = -1;
    int r = rb * TM;
    for (int j = 0; j < NE; j++)
      if (r >= off[j] && r < off[j+1]) e = j;
    block_expert[rb] = e;
  }
  for (int i = t; i < MPAD; i += 256) routed[i] = -1;
}

__global__ __launch_bounds__(256) void place_kernel(const int* __restrict__ topk,
                                                    const int* __restrict__ padded_off,
                                                    int* __restrict__ cursor,
                                                    int* __restrict__ routed)
{
  int s = blockIdx.x * 256 + threadIdx.x;   // slot id = n*2 + k
  int e = topk[s];
  int pos = padded_off[e] + atomicAdd(&cursor[e], 1);
  routed[pos] = s;
}

// ===== GEMMs: 128x128 tile, 4 waves, depth-2 counted-vmcnt (2 bufs, 33KB LDS
// -> 4-5 blocks/CU), chunk-XOR swizzle. R7 half-split schedule (h L3-hot). =====

// ---- GEMM1: h = relu(Xg @ W1[e] + b1[e]) for one hidden half ----
__global__ __launch_bounds__(256, 5) void gemm1_kernel(
    const u16* __restrict__ x16, const u16* __restrict__ w1t, const float* __restrict__ b1,
    const int* __restrict__ routed, const int* __restrict__ block_expert,
    u16* __restrict__ h, int half)
{
  int l = xcd_swz(blockIdx.x, gridDim.x);
  int rb = l >> 4, cb = l & 15;            // NCB = 16
  int e = block_expert[rb];
  if (e < 0) return;
  __shared__ __align__(16) u16 Al[2][128][32];
  __shared__ __align__(16) u16 Bl[2][128][32];
  u16* AF = &Al[0][0][0];
  u16* BF = &Bl[0][0][0];
  int t = threadIdx.x;
  int lane = t & 63, wid = t >> 6;

  int srow0 = wid*32 + (lane >> 2);
  // write-side swizzle: pre-swizzled global source column chunk (LDS dest linear)
  int sch = ((lane & 3) ^ ((lane >> 3) & 3)) * 8;

  int slot0 = routed[rb*TM + srow0];
  int slot1 = routed[rb*TM + srow0 + 16];
  int tok0 = slot0 >= 0 ? (slot0 >> 1) : 0;
  int tok1 = slot1 >= 0 ? (slot1 >> 1) : 0;
  const u16* srcA0 = x16 + (size_t)tok0 * D_MODEL + sch;
  const u16* srcA1 = x16 + (size_t)tok1 * D_MODEL + sch;
  const u16* wb = w1t + ((size_t)e*HID + (size_t)half*HHALF + (size_t)cb*128) * D_MODEL + sch;
  const u16* srcB0 = wb + (size_t)srow0 * D_MODEL;
  const u16* srcB1 = wb + (size_t)(srow0 + 16) * D_MODEL;

  int wr = wid >> 1, wc = wid & 1;
  int fr = lane & 15, fk = lane >> 4;
  int fkx8 = (fk ^ ((fr >> 1) & 3)) * 8;   // read-side swizzle (uniform per lane)
  f32x4 acc[4][4];
#pragma unroll
  for (int i = 0; i < 4; i++)
#pragma unroll
    for (int j = 0; j < 4; j++) acc[i][j] = (f32x4){0.f,0.f,0.f,0.f};

#define STG1(bo, kk) do{ \
    gload16(srcA0 + (kk), AF + (bo) + wid*1024); \
    gload16(srcA1 + (kk), AF + (bo) + wid*1024 + 512); \
    gload16(srcB0 + (kk), BF + (bo) + wid*1024); \
    gload16(srcB1 + (kk), BF + (bo) + wid*1024 + 512); } while(0)

#define CMP1(bo) do{ \
    bf16x8 af[4], bf[4]; \
    _Pragma("unroll") \
    for (int mm = 0; mm < 4; mm++) af[mm] = *(const bf16x8*)(AF + (bo) + (wr*64 + mm*16 + fr)*32 + fkx8); \
    _Pragma("unroll") \
    for (int nn = 0; nn < 4; nn++) bf[nn] = *(const bf16x8*)(BF + (bo) + (wc*64 + nn*16 + fr)*32 + fkx8); \
    _Pragma("unroll") \
    for (int mm = 0; mm < 4; mm++) \
      _Pragma("unroll") \
      for (int nn = 0; nn < 4; nn++) \
        acc[mm][nn] = __builtin_amdgcn_mfma_f32_16x16x32_bf16(af[mm], bf[nn], acc[mm][nn], 0, 0, 0); } while(0)

  const int nk = D_MODEL/32;               // 32 K-steps
  STG1(0, 0); STG1(4096, 32);
  int bo = 0;
  for (int i = 0; i < nk - 1; i++){
    WAITV(4);                              // stage i landed; i+1 in flight
    BARX();
    CMP1(bo);
    BARX();                                // all waves done reading buf bo
    if (i + 2 < nk) STG1(bo, (i+2)*32);
    bo ^= 4096;
  }
  WAITV(0); BARX(); CMP1(bo);

  int r4 = fk * 4;
#pragma unroll
  for (int nn = 0; nn < 4; nn++){
    int ct = wc*64 + nn*16 + fr;
    float bias = b1[(size_t)e*HID + (size_t)half*HHALF + cb*128 + ct];
#pragma unroll
    for (int mm = 0; mm < 4; mm++){
#pragma unroll
      for (int r = 0; r < 4; r++){
        int rt = wr*64 + mm*16 + r4 + r;
        float v = acc[mm][nn][r] + bias;
        v = v > 0.f ? v : 0.f;
        h[(size_t)(rb*TM + rt) * HHALF + cb*128 + ct] = f2bu(v);
      }
    }
  }
#undef STG1
#undef CMP1
}

// ---- GEMM2: y[slot] (+)= gate * (h @ W2[e]) for one hidden half; y is bf16 ----
__global__ __launch_bounds__(256, 5) void gemm2_kernel(
    const u16* __restrict__ h, const u16* __restrict__ w2t,
    const int* __restrict__ routed, const int* __restrict__ block_expert,
    const float* __restrict__ gates, u16* __restrict__ y, int half)
{
  int l = xcd_swz(blockIdx.x, gridDim.x);
  int rb = l >> 3, cb = l & 7;             // NCB = 8
  int e = block_expert[rb];
  if (e < 0) return;
  __shared__ __align__(16) u16 Al[2][128][32];
  __shared__ __align__(16) u16 Bl[2][128][32];
  __shared__ int   rslot[128];
  __shared__ float rgate[128];
  u16* AF = &Al[0][0][0];
  u16* BF = &Bl[0][0][0];
  int t = threadIdx.x;
  int lane = t & 63, wid = t >> 6;
  if (t < 128){
    int s = routed[rb*TM + t];
    rslot[t] = s;
    rgate[t] = (s >= 0) ? gates[s] : 0.f;
  }

  int srow0 = wid*32 + (lane >> 2);
  int sch = ((lane & 3) ^ ((lane >> 3) & 3)) * 8;
  const u16* srcA0 = h + (size_t)(rb*TM + srow0) * HHALF + sch;
  const u16* srcA1 = h + (size_t)(rb*TM + srow0 + 16) * HHALF + sch;
  const u16* wb = w2t + ((size_t)e*D_MODEL + (size_t)cb*128) * HID + (size_t)half*HHALF + sch;
  const u16* srcB0 = wb + (size_t)srow0 * HID;
  const u16* srcB1 = wb + (size_t)(srow0 + 16) * HID;

  int wr = wid >> 1, wc = wid & 1;
  int fr = lane & 15, fk = lane >> 4;
  int fkx8 = (fk ^ ((fr >> 1) & 3)) * 8;
  f32x4 acc[4][4];
#pragma unroll
  for (int i = 0; i < 4; i++)
#pragma unroll
    for (int j = 0; j < 4; j++) acc[i][j] = (f32x4){0.f,0.f,0.f,0.f};

#define STG2(bo, kk) do{ \
    gload16(srcA0 + (kk), AF + (bo) + wid*1024); \
    gload16(srcA1 + (kk), AF + (bo) + wid*1024 + 512); \
    gload16(srcB0 + (kk), BF + (bo) + wid*1024); \
    gload16(srcB1 + (kk), BF + (bo) + wid*1024 + 512); } while(0)

#define CMP2(bo) do{ \
    bf16x8 af[4], bf[4]; \
    _Pragma("unroll") \
    for (int mm = 0; mm < 4; mm++) af[mm] = *(const bf16x8*)(AF + (bo) + (wr*64 + mm*16 + fr)*32 + fkx8); \
    _Pragma("unroll") \
    for (int nn = 0; nn < 4; nn++) bf[nn] = *(const bf16x8*)(BF + (bo) + (wc*64 + nn*16 + fr)*32 + fkx8); \
    _Pragma("unroll") \
    for (int mm = 0; mm < 4; mm++) \
      _Pragma("unroll") \
      for (int nn = 0; nn < 4; nn++) \
        acc[mm][nn] = __builtin_amdgcn_mfma_f32_16x16x32_bf16(af[mm], bf[nn], acc[mm][nn], 0, 0, 0); } while(0)

  const int nk = HHALF/32;                 // 64 K-steps
  STG2(0, 0); STG2(4096, 32);
  int bo = 0;
  for (int i = 0; i < nk - 1; i++){
    WAITV(4);
    BARX();
    CMP2(bo);
    BARX();
    if (i + 2 < nk) STG2(bo, (i+2)*32);
    bo ^= 4096;
  }
  WAITV(0); BARX(); CMP2(bo);

  int r4 = fk * 4;
#pragma unroll
  for (int mm = 0; mm < 4; mm++){
#pragma unroll
    for (int r = 0; r < 4; r++){
      int rt = wr*64 + mm*16 + r4 + r;
      int slot = rslot[rt];
      if (slot < 0) continue;
      float g = rgate[rt];
#pragma unroll
      for (int nn = 0; nn < 4; nn++){
        int ct = wc*64 + nn*16 + fr;
        size_t idx = (size_t)slot * D_MODEL + cb*128 + ct;
        float val = g * acc[mm][nn][r];
        if (half == 0) y[idx] = f2bu(val);
        else           y[idx] = f2bu(b2f(y[idx]) + val);
      }
    }
  }
#undef STG2
#undef CMP2
}

// ---- combine: out[n] = y[slot0] + y[slot1] + g0*b2[e0] + g1*b2[e1] (y bf16) ----
__global__ __launch_bounds__(256) void combine_kernel(
    const u16* __restrict__ y, const int* __restrict__ topk, const float* __restrict__ gates,
    const float* __restrict__ b2, float* __restrict__ out)
{
  int i = blockIdx.x * 256 + threadIdx.x;
  int n = i >> 8;
  int d = (i & 255) * 4;
  ushort4 a4 = *(const ushort4*)(y + (size_t)(2*n)   * D_MODEL + d);
  ushort4 b4 = *(const ushort4*)(y + (size_t)(2*n+1) * D_MODEL + d);
  int e0 = topk[2*n], e1 = topk[2*n+1];
  float g0 = gates[2*n], g1 = gates[2*n+1];
  float4 c0 = *(const float4*)(b2 + (size_t)e0 * D_MODEL + d);
  float4 c1 = *(const float4*)(b2 + (size_t)e1 * D_MODEL + d);
  float4 o;
  o.x = b2f(a4.x) + b2f(b4.x) + g0*c0.x + g1*c1.x;
  o.y = b2f(a4.y) + b2f(b4.y) + g0*c0.y + g1*c1.y;
  o.z = b2f(a4.z) + b2f(b4.z) + g0*c0.z + g1*c1.z;
  o.w = b2f(a4.w) + b2f(b4.w) + g0*c0.w + g1*c1.w;
  *(float4*)(out + (size_t)n * D_MODEL + d) = o;
}

__global__ void finalize_kernel(const float* __restrict__ part_probs,
                                const float* __restrict__ part_assign,
                                const int* __restrict__ counts,
                                float* __restrict__ out_tail)
{
  __shared__ float ep[8], af[8];
  int t = threadIdx.x;
  if (t < 8){
    float s = 0.f;
    for (int b = 0; b < GATE_BLOCKS; b++) s += part_probs[b*8 + t];
    ep[t] = s / (float)NTOK;
  } else if (t < 16){
    int e = t - 8; float s = 0.f;
    for (int b = 0; b < GATE_BLOCKS; b++) s += part_assign[b*8 + e];
    af[e] = s / (float)NTOK;
  }
  __syncthreads();
  if (t == 0){
    float loss = 0.f;
    for (int e = 0; e < 8; e++) loss += ep[e] * af[e];
    out_tail[0] = loss * (float)NE;
  }
  if (t < 8){
    out_tail[1 + t]  = (float)counts[t];
    out_tail[9 + t]  = ep[t];
    out_tail[17 + t] = af[t];
  }
}

extern "C" void kernel_launch(void* const* d_in, const int* in_sizes, int n_in,
                              void* d_out, int out_size, void* d_ws, size_t ws_size,
                              hipStream_t stream)
{
  const float* x  = (const float*)d_in[0];
  const float* Wg = (const float*)d_in[1];
  const float* bg = (const float*)d_in[2];
  const float* W1 = (const float*)d_in[3];
  const float* b1 = (const float*)d_in[4];
  const float* W2 = (const float*)d_in[5];
  const float* b2 = (const float*)d_in[6];
  float* out = (float*)d_out;

  char* ws = (char*)d_ws;
  size_t o = 0;
  auto alloc = [&](size_t bytes) -> char* {
    char* p = ws + o; o = (o + bytes + 255) & ~(size_t)255; return p;
  };
  int*   topk        = (int*)   alloc((size_t)NSLOT*4);
  float* gates       = (float*) alloc((size_t)NSLOT*4);
  int*   counts      = (int*)   alloc(NE*4);
  int*   padded_off  = (int*)   alloc((NE+1)*4);
  int*   cursor      = (int*)   alloc(NE*4);
  int*   block_exp   = (int*)   alloc(MAX_RB*4);
  int*   routed      = (int*)   alloc((size_t)MPAD*4);
  float* part_probs  = (float*) alloc(GATE_BLOCKS*8*4);
  float* part_assign = (float*) alloc(GATE_BLOCKS*8*4);
  int*   part_cnt    = (int*)   alloc(GATE_BLOCKS*8*4);
  u16*   x16         = (u16*)   alloc((size_t)NTOK*D_MODEL*2);
  u16*   w1t         = (u16*)   alloc((size_t)NE*HID*D_MODEL*2);
  u16*   w2t         = (u16*)   alloc((size_t)NE*HID*D_MODEL*2);
  u16*   hbuf        = (u16*)   alloc((size_t)MPAD*HHALF*2);
  u16*   ybuf        = (u16*)   alloc((size_t)NSLOT*D_MODEL*2);
  (void)ws_size; (void)in_sizes; (void)n_in; (void)out_size;

  transpose_cvt<<<dim3(HID/32, D_MODEL/64, NE), 256, 0, stream>>>(W1, w1t, D_MODEL, HID);
  transpose_cvt<<<dim3(D_MODEL/32, HID/64, NE), 256, 0, stream>>>(W2, w2t, HID, D_MODEL);
  gate_kernel<<<GATE_BLOCKS, 256, 0, stream>>>(x, Wg, bg, topk, gates, x16, part_probs, part_assign, part_cnt);
  scan_kernel<<<1, 256, 0, stream>>>(part_cnt, counts, padded_off, cursor, block_exp, routed);
  place_kernel<<<NSLOT/256, 256, 0, stream>>>(topk, padded_off, cursor, routed);
  for (int half = 0; half < 2; half++){
    gemm1_kernel<<<16*MAX_RB, 256, 0, stream>>>(x16, w1t, b1, routed, block_exp, hbuf, half);
    gemm2_kernel<<<8*MAX_RB, 256, 0, stream>>>(hbuf, w2t, routed, block_exp, gates, ybuf, half);
  }
  combine_kernel<<<NTOK, 256, 0, stream>>>(ybuf, topk, gates, b2, out);
  finalize_kernel<<<1, 64, 0, stream>>>(part_probs, part_assign, counts, out + (size_t)NTOK*D_MODEL);
}

// Round 18
// 661.824 us; speedup vs baseline: 1.2319x; 1.1045x over previous
//
#include <hip/hip_runtime.h>
#include <stdint.h>

#define D_MODEL 1024
#define HID     4096
#define NE      8
#define NTOK    8192
#define NSLOT   (NTOK*2)
#define TM      128
#define MAX_RB  136            // padded regions fit in 136 row-blocks of 128
#define MPAD    (MAX_RB*TM)
#define HHALF   2048           // hidden split in 2 passes (L3-hot h-half schedule)
#define GATE_BLOCKS 256        // 32 tokens/block, 8 lanes/token

typedef unsigned short u16;
typedef __attribute__((ext_vector_type(8))) __bf16 bf16x8;
typedef __attribute__((ext_vector_type(4))) float  f32x4;

__device__ __forceinline__ u16 f2bu(float f){
  uint32_t u = __builtin_bit_cast(uint32_t, f);
  uint32_t r = (u + 0x7FFFu + ((u >> 16) & 1u)) >> 16;   // RNE
  return (u16)r;
}
__device__ __forceinline__ float b2f(u16 v){
  uint32_t u = ((uint32_t)v) << 16;
  return __builtin_bit_cast(float, u);
}

// async global -> LDS, 16 B per lane; lds base must be wave-uniform
__device__ __forceinline__ void gload16(const u16* src, u16* lds){
  __builtin_amdgcn_global_load_lds((const __attribute__((address_space(1))) void*)src,
                                   (__attribute__((address_space(3))) void*)lds, 16, 0, 0);
}

// bijective chunked XCD swizzle (nwg % 8 == 0)
__device__ __forceinline__ int xcd_swz(int w, int nwg){
  int q = nwg >> 3;
  return (w & 7) * q + (w >> 3);
}

// counted waits + raw barriers (T4): loads stay in flight across barriers
#define WAITV(n) do{ asm volatile("s_waitcnt vmcnt(" #n ")" ::: "memory"); \
                     __builtin_amdgcn_sched_barrier(0); }while(0)
#define BARX()   do{ __builtin_amdgcn_sched_barrier(0); \
                     __builtin_amdgcn_s_barrier(); \
                     __builtin_amdgcn_sched_barrier(0); }while(0)

// ---- transpose + fp32->bf16 cast: in[e][R][C] -> out[e][C][R] ----
__global__ __launch_bounds__(256) void transpose_cvt(const float* __restrict__ in,
                                                     u16* __restrict__ out, int R, int C)
{
  __shared__ float tile[64][33];
  int e = blockIdx.z;
  int r0 = blockIdx.y * 64, c0 = blockIdx.x * 32;
  const float* src = in + (size_t)e * R * C;
  u16* dst = out + (size_t)e * R * C;
  int t = threadIdx.x;
  int rr = t >> 3;            // 0..31
  int tc4 = (t & 7) * 4;      // 0..28
#pragma unroll
  for (int p = 0; p < 2; p++){
    int r = rr + p*32;
    float4 v = *(const float4*)(src + (size_t)(r0 + r) * C + c0 + tc4);
    tile[r][tc4+0] = v.x; tile[r][tc4+1] = v.y;
    tile[r][tc4+2] = v.z; tile[r][tc4+3] = v.w;
  }
  __syncthreads();
  int c = t >> 3;             // 0..31 output row (a column of the input tile)
  int seg = (t & 7) * 8;      // r-segment start
  u16 o[8];
#pragma unroll
  for (int j = 0; j < 8; j++) o[j] = f2bu(tile[seg + j][c]);
  *(int4*)(dst + (size_t)(c0 + c) * R + r0 + seg) = *(int4*)o;
}

// ---- gate: 8 lanes/token; logits via shfl butterfly; x->bf16 fused ----
__global__ __launch_bounds__(256) void gate_kernel(
    const float* __restrict__ x, const float* __restrict__ Wg, const float* __restrict__ bg,
    int* __restrict__ topk, float* __restrict__ gates, u16* __restrict__ x16,
    float* __restrict__ part_probs, float* __restrict__ part_assign, int* __restrict__ part_cnt)
{
  __shared__ float sp[32][8];
  __shared__ float sa[32][8];
  __shared__ int   sc[32][8];
  int t = threadIdx.x;
  int tb = t >> 3;                  // token within block (0..31)
  int g  = t & 7;                   // lane within token group
  int n  = blockIdx.x * 32 + tb;
  const float* xr = x + (size_t)n * D_MODEL;
  u16* xo = x16 + (size_t)n * D_MODEL;
  float lg[8];
#pragma unroll
  for (int e = 0; e < 8; e++) lg[e] = 0.f;
  for (int k = 0; k < 32; k++){
    int off = k*32 + g*4;           // lanes of a group cover one 128B segment
    float4 v = *(const float4*)(xr + off);
    const float* wr = Wg + (size_t)off * 8;
#pragma unroll
    for (int e = 0; e < 8; e++)
      lg[e] += v.x*wr[e] + v.y*wr[8+e] + v.z*wr[16+e] + v.w*wr[24+e];
    u16 o[4] = {f2bu(v.x), f2bu(v.y), f2bu(v.z), f2bu(v.w)};
    *(uint2*)(xo + off) = *(const uint2*)o;
  }
  // butterfly reduce across the 8-lane group (masks 1,2,4 stay in-group)
#pragma unroll
  for (int m = 1; m < 8; m <<= 1)
#pragma unroll
    for (int e = 0; e < 8; e++) lg[e] += __shfl_xor(lg[e], m);
#pragma unroll
  for (int e = 0; e < 8; e++) lg[e] += bg[e];

  float mx = lg[0];
#pragma unroll
  for (int e = 1; e < 8; e++) mx = fmaxf(mx, lg[e]);
  float p[8]; float s = 0.f;
#pragma unroll
  for (int e = 0; e < 8; e++){ p[e] = expf(lg[e]-mx); s += p[e]; }
  float inv = 1.f / s;
  int bi = 0; float best = lg[0];
#pragma unroll
  for (int e = 1; e < 8; e++) if (lg[e] > best){ best = lg[e]; bi = e; }
  int bi2 = 0; float best2 = -3.0e38f;
#pragma unroll
  for (int e = 0; e < 8; e++) if (e != bi && lg[e] > best2){ best2 = lg[e]; bi2 = e; }
  float t1 = expf(best2 - best);
  float g0 = 1.f / (1.f + t1);
  float g1 = t1 / (1.f + t1);
  if (g == 0){
    topk[2*n] = bi;  topk[2*n+1] = bi2;
    gates[2*n] = g0; gates[2*n+1] = g1;
#pragma unroll
    for (int e = 0; e < 8; e++){
      sp[tb][e] = p[e] * inv;
      sa[tb][e] = (e == bi) ? g0 : ((e == bi2) ? g1 : 0.f);
      sc[tb][e] = (e == bi || e == bi2) ? 1 : 0;
    }
  }
  __syncthreads();
  if (t < 8){
    float s2 = 0.f; for (int i = 0; i < 32; i++) s2 += sp[i][t];
    part_probs[blockIdx.x*8 + t] = s2;
  } else if (t < 16){
    int e = t - 8; float s2 = 0.f; for (int i = 0; i < 32; i++) s2 += sa[i][e];
    part_assign[blockIdx.x*8 + e] = s2;
  } else if (t < 24){
    int e = t - 16; int c = 0; for (int i = 0; i < 32; i++) c += sc[i][e];
    part_cnt[blockIdx.x*8 + e] = c;
  }
}

// ---- scan: counts, padded offsets, block->expert table, routed init ----
__global__ __launch_bounds__(256) void scan_kernel(const int* __restrict__ part_cnt,
                                                   int* __restrict__ counts,
                                                   int* __restrict__ padded_off,
                                                   int* __restrict__ cursor,
                                                   int* __restrict__ block_expert,
                                                   int* __restrict__ routed)
{
  __shared__ int off[NE+1];
  int t = threadIdx.x;
  if (t == 0){
    int o = 0; off[0] = 0;
    for (int e = 0; e < NE; e++){
      int c = 0;
      for (int b = 0; b < GATE_BLOCKS; b++) c += part_cnt[b*8 + e];
      counts[e] = c;
      o += ((c + TM - 1) / TM) * TM;
      off[e+1] = o;
    }
    for (int e = 0; e <= NE; e++) padded_off[e] = off[e];
  }
  __syncthreads();
  if (t < NE) cursor[t] = 0;
  for (int rb = t; rb < MAX_RB; rb += 256){
    int e = -1;
    int r = rb * TM;
    for (int j = 0; j < NE; j++)
      if (r >= off[j] && r < off[j+1]) e = j;
    block_expert[rb] = e;
  }
  for (int i = t; i < MPAD; i += 256) routed[i] = -1;
}

__global__ __launch_bounds__(256) void place_kernel(const int* __restrict__ topk,
                                                    const int* __restrict__ padded_off,
                                                    int* __restrict__ cursor,
                                                    int* __restrict__ routed)
{
  int s = blockIdx.x * 256 + threadIdx.x;   // slot id = n*2 + k
  int e = topk[s];
  int pos = padded_off[e] + atomicAdd(&cursor[e], 1);
  routed[pos] = s;
}

// ===== GEMMs: 128x128 tile, 4 waves, depth-3 counted-vmcnt, chunk-XOR swizzle =====
// (R7 structure: per-half dispatches so the 71 MB h-half stays L3-hot g1->g2)

// ---- GEMM1: h = relu(Xg @ W1[e] + b1[e]) for one hidden half ----
__global__ __launch_bounds__(256, 3) void gemm1_kernel(
    const u16* __restrict__ x16, const u16* __restrict__ w1t, const float* __restrict__ b1,
    const int* __restrict__ routed, const int* __restrict__ block_expert,
    u16* __restrict__ h, int half)
{
  int l = xcd_swz(blockIdx.x, gridDim.x);
  int rb = l >> 4, cb = l & 15;            // NCB = 16
  int e = block_expert[rb];
  if (e < 0) return;
  __shared__ __align__(16) u16 Al[3][128][32];
  __shared__ __align__(16) u16 Bl[3][128][32];
  u16* AF = &Al[0][0][0];
  u16* BF = &Bl[0][0][0];
  int t = threadIdx.x;
  int lane = t & 63, wid = t >> 6;

  int srow0 = wid*32 + (lane >> 2);
  // write-side swizzle: pre-swizzled global source column chunk (LDS dest linear)
  int sch = ((lane & 3) ^ ((lane >> 3) & 3)) * 8;

  int slot0 = routed[rb*TM + srow0];
  int slot1 = routed[rb*TM + srow0 + 16];
  int tok0 = slot0 >= 0 ? (slot0 >> 1) : 0;
  int tok1 = slot1 >= 0 ? (slot1 >> 1) : 0;
  const u16* srcA0 = x16 + (size_t)tok0 * D_MODEL + sch;
  const u16* srcA1 = x16 + (size_t)tok1 * D_MODEL + sch;
  const u16* wb = w1t + ((size_t)e*HID + (size_t)half*HHALF + (size_t)cb*128) * D_MODEL + sch;
  const u16* srcB0 = wb + (size_t)srow0 * D_MODEL;
  const u16* srcB1 = wb + (size_t)(srow0 + 16) * D_MODEL;

  int wr = wid >> 1, wc = wid & 1;
  int fr = lane & 15, fk = lane >> 4;
  int fkx8 = (fk ^ ((fr >> 1) & 3)) * 8;   // read-side swizzle (uniform per lane)
  f32x4 acc[4][4];
#pragma unroll
  for (int i = 0; i < 4; i++)
#pragma unroll
    for (int j = 0; j < 4; j++) acc[i][j] = (f32x4){0.f,0.f,0.f,0.f};

#define STG1(bo, kk) do{ \
    gload16(srcA0 + (kk), AF + (bo) + wid*1024); \
    gload16(srcA1 + (kk), AF + (bo) + wid*1024 + 512); \
    gload16(srcB0 + (kk), BF + (bo) + wid*1024); \
    gload16(srcB1 + (kk), BF + (bo) + wid*1024 + 512); } while(0)

#define CMP1(bo) do{ \
    bf16x8 af[4], bf[4]; \
    _Pragma("unroll") \
    for (int mm = 0; mm < 4; mm++) af[mm] = *(const bf16x8*)(AF + (bo) + (wr*64 + mm*16 + fr)*32 + fkx8); \
    _Pragma("unroll") \
    for (int nn = 0; nn < 4; nn++) bf[nn] = *(const bf16x8*)(BF + (bo) + (wc*64 + nn*16 + fr)*32 + fkx8); \
    _Pragma("unroll") \
    for (int mm = 0; mm < 4; mm++) \
      _Pragma("unroll") \
      for (int nn = 0; nn < 4; nn++) \
        acc[mm][nn] = __builtin_amdgcn_mfma_f32_16x16x32_bf16(af[mm], bf[nn], acc[mm][nn], 0, 0, 0); } while(0)

  const int nk = D_MODEL/32;               // 32 K-steps
  STG1(0, 0); STG1(4096, 32); STG1(8192, 64);
  int bo = 0;
  for (int i = 0; i < nk - 2; i++){
    WAITV(8);                              // stage i landed; i+1,i+2 in flight
    BARX();
    CMP1(bo);
    BARX();                                // all waves done reading buf
    if (i < nk - 3) STG1(bo, (i+3)*32);
    bo = (bo == 8192) ? 0 : bo + 4096;
  }
  WAITV(4); BARX(); CMP1(bo); BARX();
  bo = (bo == 8192) ? 0 : bo + 4096;
  WAITV(0); BARX(); CMP1(bo);

  int r4 = fk * 4;
#pragma unroll
  for (int nn = 0; nn < 4; nn++){
    int ct = wc*64 + nn*16 + fr;
    float bias = b1[(size_t)e*HID + (size_t)half*HHALF + cb*128 + ct];
#pragma unroll
    for (int mm = 0; mm < 4; mm++){
#pragma unroll
      for (int r = 0; r < 4; r++){
        int rt = wr*64 + mm*16 + r4 + r;
        float v = acc[mm][nn][r] + bias;
        v = v > 0.f ? v : 0.f;
        h[(size_t)(rb*TM + rt) * HHALF + cb*128 + ct] = f2bu(v);
      }
    }
  }
#undef STG1
#undef CMP1
}

// ---- GEMM2: y[slot] (+)= gate * (h @ W2[e]) for one hidden half; y is bf16 ----
__global__ __launch_bounds__(256, 3) void gemm2_kernel(
    const u16* __restrict__ h, const u16* __restrict__ w2t,
    const int* __restrict__ routed, const int* __restrict__ block_expert,
    const float* __restrict__ gates, u16* __restrict__ y, int half)
{
  int l = xcd_swz(blockIdx.x, gridDim.x);
  int rb = l >> 3, cb = l & 7;             // NCB = 8
  int e = block_expert[rb];
  if (e < 0) return;
  __shared__ __align__(16) u16 Al[3][128][32];
  __shared__ __align__(16) u16 Bl[3][128][32];
  __shared__ int   rslot[128];
  __shared__ float rgate[128];
  u16* AF = &Al[0][0][0];
  u16* BF = &Bl[0][0][0];
  int t = threadIdx.x;
  int lane = t & 63, wid = t >> 6;
  if (t < 128){
    int s = routed[rb*TM + t];
    rslot[t] = s;
    rgate[t] = (s >= 0) ? gates[s] : 0.f;
  }

  int srow0 = wid*32 + (lane >> 2);
  int sch = ((lane & 3) ^ ((lane >> 3) & 3)) * 8;
  const u16* srcA0 = h + (size_t)(rb*TM + srow0) * HHALF + sch;
  const u16* srcA1 = h + (size_t)(rb*TM + srow0 + 16) * HHALF + sch;
  const u16* wb = w2t + ((size_t)e*D_MODEL + (size_t)cb*128) * HID + (size_t)half*HHALF + sch;
  const u16* srcB0 = wb + (size_t)srow0 * HID;
  const u16* srcB1 = wb + (size_t)(srow0 + 16) * HID;

  int wr = wid >> 1, wc = wid & 1;
  int fr = lane & 15, fk = lane >> 4;
  int fkx8 = (fk ^ ((fr >> 1) & 3)) * 8;
  f32x4 acc[4][4];
#pragma unroll
  for (int i = 0; i < 4; i++)
#pragma unroll
    for (int j = 0; j < 4; j++) acc[i][j] = (f32x4){0.f,0.f,0.f,0.f};

#define STG2(bo, kk) do{ \
    gload16(srcA0 + (kk), AF + (bo) + wid*1024); \
    gload16(srcA1 + (kk), AF + (bo) + wid*1024 + 512); \
    gload16(srcB0 + (kk), BF + (bo) + wid*1024); \
    gload16(srcB1 + (kk), BF + (bo) + wid*1024 + 512); } while(0)

#define CMP2(bo) do{ \
    bf16x8 af[4], bf[4]; \
    _Pragma("unroll") \
    for (int mm = 0; mm < 4; mm++) af[mm] = *(const bf16x8*)(AF + (bo) + (wr*64 + mm*16 + fr)*32 + fkx8); \
    _Pragma("unroll") \
    for (int nn = 0; nn < 4; nn++) bf[nn] = *(const bf16x8*)(BF + (bo) + (wc*64 + nn*16 + fr)*32 + fkx8); \
    _Pragma("unroll") \
    for (int mm = 0; mm < 4; mm++) \
      _Pragma("unroll") \
      for (int nn = 0; nn < 4; nn++) \
        acc[mm][nn] = __builtin_amdgcn_mfma_f32_16x16x32_bf16(af[mm], bf[nn], acc[mm][nn], 0, 0, 0); } while(0)

  const int nk = HHALF/32;                 // 64 K-steps
  STG2(0, 0); STG2(4096, 32); STG2(8192, 64);
  int bo = 0;
  for (int i = 0; i < nk - 2; i++){
    WAITV(8);
    BARX();
    CMP2(bo);
    BARX();
    if (i < nk - 3) STG2(bo, (i+3)*32);
    bo = (bo == 8192) ? 0 : bo + 4096;
  }
  WAITV(4); BARX(); CMP2(bo); BARX();
  bo = (bo == 8192) ? 0 : bo + 4096;
  WAITV(0); BARX(); CMP2(bo);

  int r4 = fk * 4;
#pragma unroll
  for (int mm = 0; mm < 4; mm++){
#pragma unroll
    for (int r = 0; r < 4; r++){
      int rt = wr*64 + mm*16 + r4 + r;
      int slot = rslot[rt];
      if (slot < 0) continue;
      float g = rgate[rt];
#pragma unroll
      for (int nn = 0; nn < 4; nn++){
        int ct = wc*64 + nn*16 + fr;
        size_t idx = (size_t)slot * D_MODEL + cb*128 + ct;
        float val = g * acc[mm][nn][r];
        if (half == 0) y[idx] = f2bu(val);
        else           y[idx] = f2bu(b2f(y[idx]) + val);
      }
    }
  }
#undef STG2
#undef CMP2
}

// ---- combine: out[n] = y[slot0] + y[slot1] + g0*b2[e0] + g1*b2[e1] (y bf16) ----
__global__ __launch_bounds__(256) void combine_kernel(
    const u16* __restrict__ y, const int* __restrict__ topk, const float* __restrict__ gates,
    const float* __restrict__ b2, float* __restrict__ out)
{
  int i = blockIdx.x * 256 + threadIdx.x;
  int n = i >> 8;
  int d = (i & 255) * 4;
  ushort4 a4 = *(const ushort4*)(y + (size_t)(2*n)   * D_MODEL + d);
  ushort4 b4 = *(const ushort4*)(y + (size_t)(2*n+1) * D_MODEL + d);
  int e0 = topk[2*n], e1 = topk[2*n+1];
  float g0 = gates[2*n], g1 = gates[2*n+1];
  float4 c0 = *(const float4*)(b2 + (size_t)e0 * D_MODEL + d);
  float4 c1 = *(const float4*)(b2 + (size_t)e1 * D_MODEL + d);
  float4 o;
  o.x = b2f(a4.x) + b2f(b4.x) + g0*c0.x + g1*c1.x;
  o.y = b2f(a4.y) + b2f(b4.y) + g0*c0.y + g1*c1.y;
  o.z = b2f(a4.z) + b2f(b4.z) + g0*c0.z + g1*c1.z;
  o.w = b2f(a4.w) + b2f(b4.w) + g0*c0.w + g1*c1.w;
  *(float4*)(out + (size_t)n * D_MODEL + d) = o;
}

__global__ void finalize_kernel(const float* __restrict__ part_probs,
                                const float* __restrict__ part_assign,
                                const int* __restrict__ counts,
                                float* __restrict__ out_tail)
{
  __shared__ float ep[8], af[8];
  int t = threadIdx.x;
  if (t < 8){
    float s = 0.f;
    for (int b = 0; b < GATE_BLOCKS; b++) s += part_probs[b*8 + t];
    ep[t] = s / (float)NTOK;
  } else if (t < 16){
    int e = t - 8; float s = 0.f;
    for (int b = 0; b < GATE_BLOCKS; b++) s += part_assign[b*8 + e];
    af[e] = s / (float)NTOK;
  }
  __syncthreads();
  if (t == 0){
    float loss = 0.f;
    for (int e = 0; e < 8; e++) loss += ep[e] * af[e];
    out_tail[0] = loss * (float)NE;
  }
  if (t < 8){
    out_tail[1 + t]  = (float)counts[t];
    out_tail[9 + t]  = ep[t];
    out_tail[17 + t] = af[t];
  }
}

extern "C" void kernel_launch(void* const* d_in, const int* in_sizes, int n_in,
                              void* d_out, int out_size, void* d_ws, size_t ws_size,
                              hipStream_t stream)
{
  const float* x  = (const float*)d_in[0];
  const float* Wg = (const float*)d_in[1];
  const float* bg = (const float*)d_in[2];
  const float* W1 = (const float*)d_in[3];
  const float* b1 = (const float*)d_in[4];
  const float* W2 = (const float*)d_in[5];
  const float* b2 = (const float*)d_in[6];
  float* out = (float*)d_out;

  char* ws = (char*)d_ws;
  size_t o = 0;
  auto alloc = [&](size_t bytes) -> char* {
    char* p = ws + o; o = (o + bytes + 255) & ~(size_t)255; return p;
  };
  int*   topk        = (int*)   alloc((size_t)NSLOT*4);
  float* gates       = (float*) alloc((size_t)NSLOT*4);
  int*   counts      = (int*)   alloc(NE*4);
  int*   padded_off  = (int*)   alloc((NE+1)*4);
  int*   cursor      = (int*)   alloc(NE*4);
  int*   block_exp   = (int*)   alloc(MAX_RB*4);
  int*   routed      = (int*)   alloc((size_t)MPAD*4);
  float* part_probs  = (float*) alloc(GATE_BLOCKS*8*4);
  float* part_assign = (float*) alloc(GATE_BLOCKS*8*4);
  int*   part_cnt    = (int*)   alloc(GATE_BLOCKS*8*4);
  u16*   x16         = (u16*)   alloc((size_t)NTOK*D_MODEL*2);
  u16*   w1t         = (u16*)   alloc((size_t)NE*HID*D_MODEL*2);
  u16*   w2t         = (u16*)   alloc((size_t)NE*HID*D_MODEL*2);
  u16*   hbuf        = (u16*)   alloc((size_t)MPAD*HHALF*2);
  u16*   ybuf        = (u16*)   alloc((size_t)NSLOT*D_MODEL*2);
  (void)ws_size; (void)in_sizes; (void)n_in; (void)out_size;

  transpose_cvt<<<dim3(HID/32, D_MODEL/64, NE), 256, 0, stream>>>(W1, w1t, D_MODEL, HID);
  transpose_cvt<<<dim3(D_MODEL/32, HID/64, NE), 256, 0, stream>>>(W2, w2t, HID, D_MODEL);
  gate_kernel<<<GATE_BLOCKS, 256, 0, stream>>>(x, Wg, bg, topk, gates, x16, part_probs, part_assign, part_cnt);
  scan_kernel<<<1, 256, 0, stream>>>(part_cnt, counts, padded_off, cursor, block_exp, routed);
  place_kernel<<<NSLOT/256, 256, 0, stream>>>(topk, padded_off, cursor, routed);
  for (int half = 0; half < 2; half++){
    gemm1_kernel<<<16*MAX_RB, 256, 0, stream>>>(x16, w1t, b1, routed, block_exp, hbuf, half);
    gemm2_kernel<<<8*MAX_RB, 256, 0, stream>>>(hbuf, w2t, routed, block_exp, gates, ybuf, half);
  }
  combine_kernel<<<NTOK, 256, 0, stream>>>(ybuf, topk, gates, b2, out);
  finalize_kernel<<<1, 64, 0, stream>>>(part_probs, part_assign, counts, out + (size_t)NTOK*D_MODEL);
}